// Round 3
// baseline (312.177 us; speedup 1.0000x reference)
//
#include <hip/hip_runtime.h>
#include <math.h>

#define Hd 192
#define Wd 640
#define HWp (Hd * Wd)
#define NCLS 3
#define KTOP 50
#define NB 32
#define NPL (NB * NCLS)   // 96 planes
#define GPR 160           // 4-pixel groups per row (fallback scanner)
#define GPP (HWp / 4)     // 30720 groups per plane (fallback scanner)
#define SPR 40            // 16-px strips per row
#define SEGBLK 30         // scan blocks per plane (256 strips = 4096 px each)
#define SEGCAP 64         // candidate slots per scan block (E~20, 10 sigma)
#define CAP 2048          // per-plane candidate cap for ranking
#define RBK 256           // rank buckets
#define PI_F 3.14159265358979f

// ---- workspace layout ----
#define OFF_COUNTS 0            // NPL*SEGBLK ints = 11520 B
#define OFF_SEGKEY 16384        // NPL*SEGBLK*SEGCAP u64 = 1474560 B
#define OFF_PSC 0x200000        // plane_sc: NPL * 64 floats (stride-padded, 256B/plane)
#define OFF_PPI 0x206000        // plane_pi: NPL * 64 ints
#define OFF_FLAGS 0x20C000      // plane_done[NPL] + batch_done[NB] ints

// ---------------------------------------------------------------------------
// Cross-block traffic: relaxed AGENT-scope loads/stores for data, and
// ACQ_REL AGENT-scope fetch_add for the done-counter elections. The acq_rel
// atomic gives release ordering for this block's prior stores and acquire
// ordering for the winner's subsequent loads.
// ---------------------------------------------------------------------------
__device__ inline void g_store_u64(unsigned long long* p, unsigned long long v) {
  __hip_atomic_store(p, v, __ATOMIC_RELAXED, __HIP_MEMORY_SCOPE_AGENT);
}
__device__ inline unsigned long long g_load_u64(const unsigned long long* p) {
  return __hip_atomic_load((unsigned long long*)p, __ATOMIC_RELAXED,
                           __HIP_MEMORY_SCOPE_AGENT);
}
__device__ inline void g_store_i32(int* p, int v) {
  __hip_atomic_store(p, v, __ATOMIC_RELAXED, __HIP_MEMORY_SCOPE_AGENT);
}
__device__ inline int g_load_i32(const int* p) {
  return __hip_atomic_load((int*)p, __ATOMIC_RELAXED, __HIP_MEMORY_SCOPE_AGENT);
}
__device__ inline void g_store_f32(float* p, float v) {
  __hip_atomic_store(p, v, __ATOMIC_RELAXED, __HIP_MEMORY_SCOPE_AGENT);
}
__device__ inline float g_load_f32(const float* p) {
  return __hip_atomic_load((float*)p, __ATOMIC_RELAXED, __HIP_MEMORY_SCOPE_AGENT);
}
__device__ inline int done_add_acqrel(int* p) {
  return __hip_atomic_fetch_add(p, 1, __ATOMIC_ACQ_REL, __HIP_MEMORY_SCOPE_AGENT);
}

__device__ inline float fmax3(float a, float b, float c) {
  return fmaxf(fmaxf(a, b), c);
}

// ---------------------------------------------------------------------------
// Fallback 4-px-group peak scanner (exact radix rescan path only).
// ---------------------------------------------------------------------------
template <typename F>
__device__ inline void peaks_in_group(const float* __restrict__ p, int g, F&& f) {
  const int y = g / GPR;
  const int x0 = (g - y * GPR) * 4;
  const float* rm = p + y * Wd + x0;
  const float4 mq = *(const float4*)rm;
  const float ml = (x0 > 0) ? rm[-1] : -INFINITY;
  const float mr = (x0 + 4 < Wd) ? rm[4] : -INFINITY;
  float4 tq; float tl, tr;
  if (y > 0) {
    const float* rt = rm - Wd;
    tq = *(const float4*)rt;
    tl = (x0 > 0) ? rt[-1] : -INFINITY;
    tr = (x0 + 4 < Wd) ? rt[4] : -INFINITY;
  } else {
    tq.x = tq.y = tq.z = tq.w = -INFINITY; tl = -INFINITY; tr = -INFINITY;
  }
  float4 bq; float bl, br;
  if (y < Hd - 1) {
    const float* rb = rm + Wd;
    bq = *(const float4*)rb;
    bl = (x0 > 0) ? rb[-1] : -INFINITY;
    br = (x0 + 4 < Wd) ? rb[4] : -INFINITY;
  } else {
    bq.x = bq.y = bq.z = bq.w = -INFINITY; bl = -INFINITY; br = -INFINITY;
  }
  const float c0 = fmax3(tl, ml, bl);
  const float c1 = fmax3(tq.x, mq.x, bq.x);
  const float c2 = fmax3(tq.y, mq.y, bq.y);
  const float c3 = fmax3(tq.z, mq.z, bq.z);
  const float c4 = fmax3(tq.w, mq.w, bq.w);
  const float c5 = fmax3(tr, mr, br);
  const int base = y * Wd + x0;
  if (mq.x == fmax3(c0, c1, c2)) f(__float_as_uint(mq.x), base + 0);
  if (mq.y == fmax3(c1, c2, c3)) f(__float_as_uint(mq.y), base + 1);
  if (mq.z == fmax3(c2, c3, c4)) f(__float_as_uint(mq.z), base + 2);
  if (mq.w == fmax3(c3, c4, c5)) f(__float_as_uint(mq.w), base + 3);
}

template <typename F>
__device__ inline void for_each_peak_plane(const float* __restrict__ p, int tid,
                                           int nth, F&& f) {
  for (int g = tid; g < GPP; g += nth) peaks_in_group(p, g, f);
}

// key = (bits << 32) | ~idx : strict u64 '>' == (value desc, idx asc).
__device__ inline unsigned long long mk_key(unsigned int bits, int idx) {
  return ((unsigned long long)bits << 32) | (unsigned int)~idx;
}

// Monotone bucket over value bits; ~uniform on [0.995, 1.0); clamped outside.
__device__ inline int bucket_of(unsigned int bits) {
  const unsigned int base = __float_as_uint(0.995f);
  if (bits <= base) return 0;
  unsigned int d = (bits - base) >> 9;
  return d > 255u ? 255 : (int)d;
}

// ---------------------------------------------------------------------------
// 16-px row segment, all named fields (registers only — no arrays).
// ---------------------------------------------------------------------------
struct Row16 {
  float4 q0, q1, q2, q3;
  float l, r;
};

__device__ inline Row16 load_row16(const float* __restrict__ rp, int x0, bool valid) {
  Row16 o;
  if (valid) {
    o.q0 = *(const float4*)(rp);
    o.q1 = *(const float4*)(rp + 4);
    o.q2 = *(const float4*)(rp + 8);
    o.q3 = *(const float4*)(rp + 12);
    o.l = (x0 > 0) ? rp[-1] : -INFINITY;
    o.r = (x0 + 16 < Wd) ? rp[16] : -INFINITY;
  } else {
    o.q0.x = o.q0.y = o.q0.z = o.q0.w = -INFINITY;
    o.q1 = o.q0; o.q2 = o.q0; o.q3 = o.q0;
    o.l = -INFINITY; o.r = -INFINITY;
  }
  return o;
}

__device__ inline float4 max3v(const float4 a, const float4 b, const float4 c) {
  float4 o;
  o.x = fmax3(a.x, b.x, c.x);
  o.y = fmax3(a.y, b.y, c.y);
  o.z = fmax3(a.z, b.z, c.z);
  o.w = fmax3(a.w, b.w, c.w);
  return o;
}

__device__ inline void inv3(const float* m, float* o) {
  float a = m[0], b = m[1], c = m[2];
  float d = m[3], e = m[4], f = m[5];
  float g = m[6], h = m[7], i = m[8];
  float A = e * i - f * h;
  float B = -(d * i - f * g);
  float C = d * h - e * g;
  float det = a * A + b * B + c * C;
  float id = 1.0f / det;
  o[0] = A * id;            o[1] = -(b * i - c * h) * id; o[2] = (b * f - c * e) * id;
  o[3] = B * id;            o[4] = (a * i - c * g) * id;  o[5] = -(a * f - c * d) * id;
  o[6] = C * id;            o[7] = -(a * h - b * g) * id; o[8] = (a * e - b * d) * id;
}

__device__ inline float wrap_pi(float a) {
  if (a > PI_F) return a - 2.0f * PI_F;
  if (a < -PI_F) return a + 2.0f * PI_F;
  return a;
}

__constant__ float DIM_REF_C[9] = {3.88f, 1.63f, 1.53f,
                                   0.84f, 1.76f, 0.66f,
                                   1.78f, 1.52f, 1.78f};

// ---------------------------------------------------------------------------
// Tiny init kernel: zero the NPL+NB = 128 election counters. Replaces the
// hipMemsetAsync node (unvetted in this harness's graph-capture path).
// ---------------------------------------------------------------------------
__global__ __launch_bounds__(128) void zero_flags_kernel(int* __restrict__ flags) {
  flags[threadIdx.x] = 0;
}

// ---------------------------------------------------------------------------
// Fused kernel: scan -> (last scan block of plane) rank -> (last plane of
// batch) decode. Grid NPL*SEGBLK x 256. plane = blk % NPL so all planes finish
// ~together and the 96 plane-ranks run concurrently at the tail. The
// last-block-done pattern never WAITS (each non-winner exits), so no
// co-residency requirement.
// ---------------------------------------------------------------------------
__global__ __launch_bounds__(256) void fused_kernel(
    const float* __restrict__ heat,
    const float* __restrict__ regr,      // [B][8][HWp]
    const float* __restrict__ trans_mat, // [B][3][3]
    const float* __restrict__ K_mat,     // [B][3][3]
    const float* __restrict__ img_size,  // [B][2]
    int* __restrict__ counts,
    unsigned long long* __restrict__ segkey,
    float* __restrict__ plane_sc,        // [NPL][64] (stride-padded)
    int* __restrict__ plane_pi,          // [NPL][64]
    int* __restrict__ plane_done,        // [NPL], zeroed by zero_flags_kernel
    int* __restrict__ batch_done,        // [NB], zeroed by zero_flags_kernel
    float* __restrict__ out) {           // [B*50][14]
  const int blk = blockIdx.x;
  const int plane = blk % NPL;
  const int sub = blk / NPL;
  const int tid = threadIdx.x;

  __shared__ unsigned long long s_key[CAP];   // 16 KB raw candidates
  __shared__ unsigned long long c_key[CAP];   // 16 KB bucket-grouped (aliases fb_hist)
  __shared__ unsigned long long s_k[SEGCAP];  // scan-phase segment slots
  __shared__ int s_off[SEGBLK + 1];
  __shared__ int cnt[RBK], suf[RBK], cur[RBK];
  __shared__ float d_sc[NCLS * KTOP];
  __shared__ int d_pi[NCLS * KTOP];
  __shared__ int sel[KTOP];
  __shared__ int s_n, s_flag, s_M, s_fast, s_win, s_last;
  __shared__ int s_fbB, s_fbAbove, s_fbT, s_fbCnt;

  if (tid == 0) s_n = 0;
  __syncthreads();

  // ======================= scan phase =======================
  {
    const int strip = sub * 256 + tid;
    const int y = strip / SPR;
    const int x0 = (strip - y * SPR) * 16;
    const float* pm = heat + (size_t)plane * HWp + y * Wd + x0;

    const Row16 m = load_row16(pm, x0, true);
    const Row16 t = load_row16(pm - Wd, x0, y > 0);
    const Row16 bt = load_row16(pm + Wd, x0, y < Hd - 1);

    const float cl = fmax3(t.l, m.l, bt.l);
    const float cr = fmax3(t.r, m.r, bt.r);
    const float4 c0 = max3v(t.q0, m.q0, bt.q0);
    const float4 c1 = max3v(t.q1, m.q1, bt.q1);
    const float4 c2 = max3v(t.q2, m.q2, bt.q2);
    const float4 c3 = max3v(t.q3, m.q3, bt.q3);

    const float TH = 0.995f;
    const int base = y * Wd + x0;
#define EMIT(V, W0, W1, W2, J)                                         \
    if ((V) >= TH && (V) == fmax3((W0), (W1), (W2))) {                 \
      int slot = atomicAdd(&s_n, 1);                                   \
      if (slot < SEGCAP) s_k[slot] = mk_key(__float_as_uint(V), base + (J)); \
    }
    EMIT(m.q0.x, cl,   c0.x, c0.y, 0)
    EMIT(m.q0.y, c0.x, c0.y, c0.z, 1)
    EMIT(m.q0.z, c0.y, c0.z, c0.w, 2)
    EMIT(m.q0.w, c0.z, c0.w, c1.x, 3)
    EMIT(m.q1.x, c0.w, c1.x, c1.y, 4)
    EMIT(m.q1.y, c1.x, c1.y, c1.z, 5)
    EMIT(m.q1.z, c1.y, c1.z, c1.w, 6)
    EMIT(m.q1.w, c1.z, c1.w, c2.x, 7)
    EMIT(m.q2.x, c1.w, c2.x, c2.y, 8)
    EMIT(m.q2.y, c2.x, c2.y, c2.z, 9)
    EMIT(m.q2.z, c2.y, c2.z, c2.w, 10)
    EMIT(m.q2.w, c2.z, c2.w, c3.x, 11)
    EMIT(m.q3.x, c2.w, c3.x, c3.y, 12)
    EMIT(m.q3.y, c3.x, c3.y, c3.z, 13)
    EMIT(m.q3.z, c3.y, c3.z, c3.w, 14)
    EMIT(m.q3.w, c3.z, c3.w, cr,   15)
#undef EMIT
  }

  __syncthreads();
  {
    const int n = s_n;
    const int cidx = plane * SEGBLK + sub;
    if (tid == 0) g_store_i32(&counts[cidx], n);
    const int nn = n < SEGCAP ? n : SEGCAP;
    if (tid < nn)
      g_store_u64(&segkey[(size_t)cidx * SEGCAP + tid], s_k[tid]);
  }
  __syncthreads();
  if (tid == 0) {
    const int r = done_add_acqrel(&plane_done[plane]);  // release our stores
    s_win = (r == SEGBLK - 1);                          // acquire others'
  }
  __syncthreads();
  if (!s_win) return;

  // ======================= rank phase (plane winner) =======================
  if (tid == 0) { s_flag = 0; s_off[0] = 0; }
  __syncthreads();
  if (tid < SEGBLK) {
    int nv = g_load_i32(&counts[plane * SEGBLK + tid]);
    if (nv > SEGCAP) { atomicOr(&s_flag, 1); nv = SEGCAP; }
    s_off[tid + 1] = nv;
  }
  __syncthreads();
  if (tid == 0) {
    int acc = 0;
    for (int i = 1; i <= SEGBLK; ++i) { acc += s_off[i]; s_off[i] = acc; }
    s_M = acc;
    s_fast = (s_flag == 0) && (acc >= KTOP) && (acc <= CAP);
  }
  __syncthreads();

  if (s_fast) {
    const unsigned long long* pk = segkey + (size_t)plane * SEGBLK * SEGCAP;
    for (int i = tid; i < SEGBLK * SEGCAP; i += 256) {
      const int sg = i >> 6;          // / SEGCAP
      const int j = i & (SEGCAP - 1);
      const int o = s_off[sg];
      const int nsg = s_off[sg + 1] - o;
      if (j < nsg) s_key[o + j] = g_load_u64(&pk[i]);
    }
    __syncthreads();
  } else {
    // Exact radix-select rescan (values >= 0); never triggers on this data.
    const float* hp = heat + (size_t)plane * HWp;
    unsigned int* fb_hist = (unsigned int*)c_key;  // alias: c_key unused yet
    for (int i = tid; i < 1024; i += 256) fb_hist[i] = 0;
    __syncthreads();
    for_each_peak_plane(hp, tid, 256, [&](unsigned int bits, int idx) {
      unsigned int bkt = bits >> 20; if (bkt > 1023u) bkt = 1023u;
      atomicAdd(&fb_hist[bkt], 1u);
    });
    __syncthreads();
    if (tid == 0) {
      int acc = 0, Bs = -1;
      for (int bkt = 1023; bkt >= 0; --bkt) {
        int cc = (int)fb_hist[bkt];
        if (acc + cc >= KTOP) { Bs = bkt; s_fbAbove = acc; break; }
        acc += cc;
      }
      s_fbB = Bs;
      if (Bs < 0) s_fbAbove = acc;
    }
    __syncthreads();
    const int Bs = s_fbB;
    unsigned int T;
    if (Bs < 0) {
      T = 0;  // fewer than 50 peaks total: take them all
    } else {
      for (int i = tid; i < 1024; i += 256) fb_hist[i] = 0;
      __syncthreads();
      for_each_peak_plane(hp, tid, 256, [&](unsigned int bits, int idx) {
        unsigned int bkt = bits >> 20; if (bkt > 1023u) bkt = 1023u;
        if ((int)bkt == Bs) atomicAdd(&fb_hist[(bits >> 10) & 1023], 1u);
      });
      __syncthreads();
      if (tid == 0) {
        int acc = s_fbAbove, Ss = 0;
        for (int sb = 1023; sb >= 0; --sb) {
          int cc = (int)fb_hist[sb];
          if (acc + cc >= KTOP) { Ss = sb; break; }
          acc += cc;
        }
        s_fbT = (int)(((unsigned int)Bs << 20) | ((unsigned int)Ss << 10));
      }
      __syncthreads();
      T = (unsigned int)s_fbT;
    }
    if (tid == 0) s_fbCnt = 0;
    __syncthreads();
    for_each_peak_plane(hp, tid, 256, [&](unsigned int bits, int idx) {
      if (bits >= T) {
        int slot = atomicAdd(&s_fbCnt, 1);
        if (slot < CAP) s_key[slot] = mk_key(bits, idx);
      }
    });
    __syncthreads();
    if (tid == 0) s_M = s_fbCnt < CAP ? s_fbCnt : CAP;
    __syncthreads();
  }
  const int M = s_M;

  // ---- O(M) counting-sort rank: (value desc, idx asc) order. ----
  cnt[tid] = 0;
  cur[tid] = 0;
  __syncthreads();
  for (int i = tid; i < M; i += 256)
    atomicAdd(&cnt[bucket_of((unsigned int)(s_key[i] >> 32))], 1);
  __syncthreads();
  // Parallel suffix-sum (Hillis-Steele), replaces the serial 256-iter loop.
  suf[tid] = cnt[tid];
  __syncthreads();
#pragma unroll
  for (int d = 1; d < RBK; d <<= 1) {
    const int v = (tid + d < RBK) ? suf[tid + d] : 0;
    __syncthreads();
    suf[tid] += v;
    __syncthreads();
  }
  {
    const int excl = suf[tid] - cnt[tid];  // count of keys in buckets > tid
    __syncthreads();
    suf[tid] = excl;
  }
  __syncthreads();
  for (int i = tid; i < M; i += 256) {
    const unsigned long long k = s_key[i];
    const int bq = bucket_of((unsigned int)(k >> 32));
    const int slot = suf[bq] + atomicAdd(&cur[bq], 1);
    c_key[slot] = k;
  }
  __syncthreads();
  {
    float* psc = plane_sc + plane * 64;
    int* ppi = plane_pi + plane * 64;
    for (int i = tid; i < M; i += 256) {
      const unsigned long long k = c_key[i];
      const int bq = bucket_of((unsigned int)(k >> 32));
      const int st = suf[bq];
      const int nb = cnt[bq];
      int rank = st;
      for (int tt = st; tt < st + nb; ++tt) rank += (c_key[tt] > k);
      if (rank < KTOP) {
        g_store_f32(&psc[rank], __uint_as_float((unsigned int)(k >> 32)));
        g_store_i32(&ppi[rank], (int)~((unsigned int)k));
      }
    }
    for (int s2 = M + tid; s2 < KTOP; s2 += 256) {
      g_store_f32(&psc[s2], 0.0f);
      g_store_i32(&ppi[s2], 0);
    }
  }
  __syncthreads();
  if (tid == 0) {
    const int r = done_add_acqrel(&batch_done[plane / NCLS]);  // release+acquire
    s_last = (r == NCLS - 1);
  }
  __syncthreads();
  if (!s_last) return;

  // ======================= decode phase (batch winner) =======================
  const int b = plane / NCLS;
  if (tid < NCLS * KTOP) {
    const int c = tid / KTOP;
    const int k2 = tid - c * KTOP;
    d_sc[tid] = g_load_f32(&plane_sc[(b * NCLS + c) * 64 + k2]);
    d_pi[tid] = g_load_i32(&plane_pi[(b * NCLS + c) * 64 + k2]);
  }
  __syncthreads();

  // Batch-level top-50 over 150 scores (tie: lower flattened position wins).
  if (tid < NCLS * KTOP) {
    const float v = d_sc[tid];
    int rank = 0;
    for (int j = 0; j < NCLS * KTOP; ++j) {
      const float w = d_sc[j];
      rank += (w > v) || (w == v && j < tid);
    }
    if (rank < KTOP) sel[rank] = tid;
  }
  __syncthreads();

  if (tid < KTOP) {
    const int i = sel[tid];
    const int cls = i / KTOP;
    const float score = d_sc[i];
    const int ind = d_pi[i];
    const float ys = (float)(ind / Wd);
    const float xs = (float)(ind - (ind / Wd) * Wd);

    const float* rb = regr + (size_t)b * 8 * HWp + ind;
    const float r0 = rb[0 * HWp], r1 = rb[1 * HWp], r2 = rb[2 * HWp], r3 = rb[3 * HWp];
    const float r4 = rb[4 * HWp], r5 = rb[5 * HWp], r6 = rb[6 * HWp], r7 = rb[7 * HWp];

    float tm[9], km[9], tmi[9], kmi[9];
#pragma unroll
    for (int q = 0; q < 9; ++q) { tm[q] = trans_mat[b * 9 + q]; km[q] = K_mat[b * 9 + q]; }
    inv3(tm, tmi);
    inv3(km, kmi);

    const float px = xs + r1, py = ys + r2;
    const float gx = tmi[0] * px + tmi[1] * py + tmi[2];
    const float gy = tmi[3] * px + tmi[4] * py + tmi[5];
    const float gz = tmi[6] * px + tmi[7] * py + tmi[8];
    const float depth = r0 * 16.32f + 28.01f;
    const float qx = gx * depth, qy = gy * depth, qz = gz * depth;
    const float lx = kmi[0] * qx + kmi[1] * qy + kmi[2] * qz;
    float ly = kmi[3] * qx + kmi[4] * qy + kmi[5] * qz;
    const float lz = kmi[6] * qx + kmi[7] * qy + kmi[8] * qz;

    const float d0 = expf(r3) * DIM_REF_C[cls * 3 + 0];
    const float d1 = expf(r4) * DIM_REF_C[cls * 3 + 1];
    const float d2 = expf(r5) * DIM_REF_C[cls * 3 + 2];
    ly += d1 * 0.5f;

    const float ray = atanf(lx / (lz + 1e-7f));
    float alpha = atanf(r6 / (r7 + 1e-7f));
    alpha += (r7 >= 0.0f) ? -PI_F * 0.5f : PI_F * 0.5f;
    const float roty = wrap_pi(alpha + ray);
    alpha = wrap_pi(alpha);

    const float SX[8] = {-0.5f, 0.5f, 0.5f, 0.5f, 0.5f, -0.5f, -0.5f, -0.5f};
    const float SY[8] = {-1.0f, -1.0f, 0.0f, 0.0f, -1.0f, -1.0f, 0.0f, 0.0f};
    const float SZ[8] = {-0.5f, -0.5f, -0.5f, 0.5f, 0.5f, 0.5f, 0.5f, -0.5f};
    const float cr = cosf(roty), sr = sinf(roty);
    float minx = INFINITY, maxx = -INFINITY, miny = INFINITY, maxy = -INFINITY;
#pragma unroll
    for (int j = 0; j < 8; ++j) {
      const float ax = d0 * SX[j], ay = d1 * SY[j], az = d2 * SZ[j];
      const float cx = cr * ax + sr * az + lx;
      const float cy = ay + ly;
      const float cz = -sr * ax + cr * az + lz;
      const float ppx = km[0] * cx + km[1] * cy + km[2] * cz;
      const float ppy = km[3] * cx + km[4] * cy + km[5] * cz;
      const float ppz = km[6] * cx + km[7] * cy + km[8] * cz;
      const float X = ppx / ppz, Y = ppy / ppz;
      minx = fminf(minx, X); maxx = fmaxf(maxx, X);
      miny = fminf(miny, Y); maxy = fmaxf(maxy, Y);
    }
    const float Wi = img_size[b * 2 + 0], Hi = img_size[b * 2 + 1];
    const float xmin = fminf(fmaxf(minx, 0.0f), Wi);
    const float ymin = fminf(fmaxf(miny, 0.0f), Hi);
    const float xmax = fminf(fmaxf(maxx, 0.0f), Wi);
    const float ymax = fminf(fmaxf(maxy, 0.0f), Hi);

    float* o = out + (size_t)(b * KTOP + tid) * 14;
    if (score > 0.25f) {
      o[0] = (float)cls; o[1] = alpha;
      o[2] = xmin; o[3] = ymin; o[4] = xmax; o[5] = ymax;
      o[6] = d1; o[7] = d2; o[8] = d0;   // dims rolled by -1
      o[9] = lx; o[10] = ly; o[11] = lz;
      o[12] = roty; o[13] = score;
    } else {
#pragma unroll
      for (int q = 0; q < 14; ++q) o[q] = 0.0f;
    }
  }
}

// ---------------------------------------------------------------------------

extern "C" void kernel_launch(void* const* d_in, const int* in_sizes, int n_in,
                              void* d_out, int out_size, void* d_ws, size_t ws_size,
                              hipStream_t stream) {
  const float* heat = (const float*)d_in[0];  // [32,3,192,640]
  const float* regr = (const float*)d_in[1];  // [32,8,192,640]
  const float* tmat = (const float*)d_in[2];  // [32,3,3]
  const float* kmat = (const float*)d_in[3];  // [32,3,3]
  const float* isz = (const float*)d_in[4];   // [32,2]

  char* ws = (char*)d_ws;
  int* counts = (int*)(ws + OFF_COUNTS);
  unsigned long long* segkey = (unsigned long long*)(ws + OFF_SEGKEY);
  float* plane_sc = (float*)(ws + OFF_PSC);
  int* plane_pi = (int*)(ws + OFF_PPI);
  int* plane_done = (int*)(ws + OFF_FLAGS);
  int* batch_done = plane_done + NPL;

  // Zero election counters (128 ints) with a plain kernel launch — the only
  // launch type proven safe in this harness's graph-capture path. Required
  // every launch: harness poisons the workspace between runs.
  zero_flags_kernel<<<1, 128, 0, stream>>>(plane_done);
  fused_kernel<<<NPL * SEGBLK, 256, 0, stream>>>(
      heat, regr, tmat, kmat, isz,
      counts, segkey, plane_sc, plane_pi, plane_done, batch_done,
      (float*)d_out);
}

// Round 4
// 211.451 us; speedup vs baseline: 1.4764x; 1.4764x over previous
//
#include <hip/hip_runtime.h>
#include <math.h>

#define Hd 192
#define Wd 640
#define HWp (Hd * Wd)
#define NCLS 3
#define KTOP 50
#define NB 32
#define NPL (NB * NCLS)   // 96 planes
#define GPR 160           // 4-pixel groups per row (fallback scanner)
#define GPP (HWp / 4)     // 30720 groups per plane (fallback scanner)
#define SPR 40            // 16-px strips per row
#define SEGBLK 30         // scan blocks per plane (256 strips = 4096 px each)
#define SEGCAP 64         // candidate slots per scan block (E~20, 10 sigma)
#define CAP 2048          // per-plane candidate cap for ranking
#define RBK 256           // rank buckets
#define PI_F 3.14159265358979f

// ---- workspace layout (no flags; coherence via kernel boundaries) ----
#define OFF_COUNTS 0            // NPL*SEGBLK ints = 11520 B
#define OFF_SEGKEY 16384        // NPL*SEGBLK*SEGCAP u64 = 1474560 B
#define OFF_PSC 0x200000        // plane_sc: NPL * 64 floats (256B stride/plane)
#define OFF_PPI 0x206000        // plane_pi: NPL * 64 ints

__device__ inline float fmax3(float a, float b, float c) {
  return fmaxf(fmaxf(a, b), c);
}

// ---------------------------------------------------------------------------
// Fallback 4-px-group peak scanner (exact radix rescan path only).
// ---------------------------------------------------------------------------
template <typename F>
__device__ inline void peaks_in_group(const float* __restrict__ p, int g, F&& f) {
  const int y = g / GPR;
  const int x0 = (g - y * GPR) * 4;
  const float* rm = p + y * Wd + x0;
  const float4 mq = *(const float4*)rm;
  const float ml = (x0 > 0) ? rm[-1] : -INFINITY;
  const float mr = (x0 + 4 < Wd) ? rm[4] : -INFINITY;
  float4 tq; float tl, tr;
  if (y > 0) {
    const float* rt = rm - Wd;
    tq = *(const float4*)rt;
    tl = (x0 > 0) ? rt[-1] : -INFINITY;
    tr = (x0 + 4 < Wd) ? rt[4] : -INFINITY;
  } else {
    tq.x = tq.y = tq.z = tq.w = -INFINITY; tl = -INFINITY; tr = -INFINITY;
  }
  float4 bq; float bl, br;
  if (y < Hd - 1) {
    const float* rb = rm + Wd;
    bq = *(const float4*)rb;
    bl = (x0 > 0) ? rb[-1] : -INFINITY;
    br = (x0 + 4 < Wd) ? rb[4] : -INFINITY;
  } else {
    bq.x = bq.y = bq.z = bq.w = -INFINITY; bl = -INFINITY; br = -INFINITY;
  }
  const float c0 = fmax3(tl, ml, bl);
  const float c1 = fmax3(tq.x, mq.x, bq.x);
  const float c2 = fmax3(tq.y, mq.y, bq.y);
  const float c3 = fmax3(tq.z, mq.z, bq.z);
  const float c4 = fmax3(tq.w, mq.w, bq.w);
  const float c5 = fmax3(tr, mr, br);
  const int base = y * Wd + x0;
  if (mq.x == fmax3(c0, c1, c2)) f(__float_as_uint(mq.x), base + 0);
  if (mq.y == fmax3(c1, c2, c3)) f(__float_as_uint(mq.y), base + 1);
  if (mq.z == fmax3(c2, c3, c4)) f(__float_as_uint(mq.z), base + 2);
  if (mq.w == fmax3(c3, c4, c5)) f(__float_as_uint(mq.w), base + 3);
}

template <typename F>
__device__ inline void for_each_peak_plane(const float* __restrict__ p, int tid,
                                           int nth, F&& f) {
  for (int g = tid; g < GPP; g += nth) peaks_in_group(p, g, f);
}

// key = (bits << 32) | ~idx : strict u64 '>' == (value desc, idx asc).
__device__ inline unsigned long long mk_key(unsigned int bits, int idx) {
  return ((unsigned long long)bits << 32) | (unsigned int)~idx;
}

// Monotone bucket over value bits; ~uniform on [0.995, 1.0); clamped outside.
__device__ inline int bucket_of(unsigned int bits) {
  const unsigned int base = __float_as_uint(0.995f);
  if (bits <= base) return 0;
  unsigned int d = (bits - base) >> 9;
  return d > 255u ? 255 : (int)d;
}

// ---------------------------------------------------------------------------
// 16-px row segment, all named fields (registers only — no arrays).
// ---------------------------------------------------------------------------
struct Row16 {
  float4 q0, q1, q2, q3;
  float l, r;
};

__device__ inline Row16 load_row16(const float* __restrict__ rp, int x0, bool valid) {
  Row16 o;
  if (valid) {
    o.q0 = *(const float4*)(rp);
    o.q1 = *(const float4*)(rp + 4);
    o.q2 = *(const float4*)(rp + 8);
    o.q3 = *(const float4*)(rp + 12);
    o.l = (x0 > 0) ? rp[-1] : -INFINITY;
    o.r = (x0 + 16 < Wd) ? rp[16] : -INFINITY;
  } else {
    o.q0.x = o.q0.y = o.q0.z = o.q0.w = -INFINITY;
    o.q1 = o.q0; o.q2 = o.q0; o.q3 = o.q0;
    o.l = -INFINITY; o.r = -INFINITY;
  }
  return o;
}

__device__ inline float4 max3v(const float4 a, const float4 b, const float4 c) {
  float4 o;
  o.x = fmax3(a.x, b.x, c.x);
  o.y = fmax3(a.y, b.y, c.y);
  o.z = fmax3(a.z, b.z, c.z);
  o.w = fmax3(a.w, b.w, c.w);
  return o;
}

__device__ inline void inv3(const float* m, float* o) {
  float a = m[0], b = m[1], c = m[2];
  float d = m[3], e = m[4], f = m[5];
  float g = m[6], h = m[7], i = m[8];
  float A = e * i - f * h;
  float B = -(d * i - f * g);
  float C = d * h - e * g;
  float det = a * A + b * B + c * C;
  float id = 1.0f / det;
  o[0] = A * id;            o[1] = -(b * i - c * h) * id; o[2] = (b * f - c * e) * id;
  o[3] = B * id;            o[4] = (a * i - c * g) * id;  o[5] = -(a * f - c * d) * id;
  o[6] = C * id;            o[7] = -(a * h - b * g) * id; o[8] = (a * e - b * d) * id;
}

__device__ inline float wrap_pi(float a) {
  if (a > PI_F) return a - 2.0f * PI_F;
  if (a < -PI_F) return a + 2.0f * PI_F;
  return a;
}

__constant__ float DIM_REF_C[9] = {3.88f, 1.63f, 1.53f,
                                   0.84f, 1.76f, 0.66f,
                                   1.78f, 1.52f, 1.78f};

// ---------------------------------------------------------------------------
// Kernel 1: scan. 96 planes x 30 blocks x 256 threads, one 16-px strip per
// thread. LDS atomics only; plain global stores (visibility to kernel 2 via
// the stream-order kernel boundary — NO device-scope fences anywhere).
// ---------------------------------------------------------------------------
__global__ __launch_bounds__(256) void scan_kernel(
    const float* __restrict__ heat,
    int* __restrict__ counts,                 // [NPL*SEGBLK]
    unsigned long long* __restrict__ segkey) {// [NPL*SEGBLK][SEGCAP]
  const int blk = blockIdx.x;
  const int plane = blk / SEGBLK;
  const int sub = blk - plane * SEGBLK;
  __shared__ unsigned long long s_k[SEGCAP];
  __shared__ int s_n;
  if (threadIdx.x == 0) s_n = 0;
  __syncthreads();

  const int strip = sub * 256 + threadIdx.x;
  const int y = strip / SPR;
  const int x0 = (strip - y * SPR) * 16;
  const float* pm = heat + (size_t)plane * HWp + y * Wd + x0;

  const Row16 m = load_row16(pm, x0, true);
  const Row16 t = load_row16(pm - Wd, x0, y > 0);
  const Row16 b = load_row16(pm + Wd, x0, y < Hd - 1);

  const float cl = fmax3(t.l, m.l, b.l);
  const float cr = fmax3(t.r, m.r, b.r);
  const float4 c0 = max3v(t.q0, m.q0, b.q0);
  const float4 c1 = max3v(t.q1, m.q1, b.q1);
  const float4 c2 = max3v(t.q2, m.q2, b.q2);
  const float4 c3 = max3v(t.q3, m.q3, b.q3);

  const float TH = 0.995f;
  const int base = y * Wd + x0;
#define EMIT(V, W0, W1, W2, J)                                         \
  if ((V) >= TH && (V) == fmax3((W0), (W1), (W2))) {                   \
    int slot = atomicAdd(&s_n, 1);                                     \
    if (slot < SEGCAP) s_k[slot] = mk_key(__float_as_uint(V), base + (J)); \
  }
  EMIT(m.q0.x, cl,   c0.x, c0.y, 0)
  EMIT(m.q0.y, c0.x, c0.y, c0.z, 1)
  EMIT(m.q0.z, c0.y, c0.z, c0.w, 2)
  EMIT(m.q0.w, c0.z, c0.w, c1.x, 3)
  EMIT(m.q1.x, c0.w, c1.x, c1.y, 4)
  EMIT(m.q1.y, c1.x, c1.y, c1.z, 5)
  EMIT(m.q1.z, c1.y, c1.z, c1.w, 6)
  EMIT(m.q1.w, c1.z, c1.w, c2.x, 7)
  EMIT(m.q2.x, c1.w, c2.x, c2.y, 8)
  EMIT(m.q2.y, c2.x, c2.y, c2.z, 9)
  EMIT(m.q2.z, c2.y, c2.z, c2.w, 10)
  EMIT(m.q2.w, c2.z, c2.w, c3.x, 11)
  EMIT(m.q3.x, c2.w, c3.x, c3.y, 12)
  EMIT(m.q3.y, c3.x, c3.y, c3.z, 13)
  EMIT(m.q3.z, c3.y, c3.z, c3.w, 14)
  EMIT(m.q3.w, c3.z, c3.w, cr,   15)
#undef EMIT

  __syncthreads();
  const int n = s_n;
  if (threadIdx.x == 0) counts[blk] = n;
  const int nn = n < SEGCAP ? n : SEGCAP;
  if (threadIdx.x < nn)
    segkey[(size_t)blk * SEGCAP + threadIdx.x] = s_k[threadIdx.x];
}

// ---------------------------------------------------------------------------
// Kernel 2: per-plane rank. 96 blocks x 256 threads — one plane per block
// (3x the CU parallelism of the old 32x768 rank3). Writes plane top-50 to
// workspace with plain stores; kernel-3 boundary provides coherence.
// ---------------------------------------------------------------------------
__global__ __launch_bounds__(256) void rank_kernel(
    const float* __restrict__ heat,
    const int* __restrict__ counts,
    const unsigned long long* __restrict__ segkey,
    float* __restrict__ plane_sc,        // [NPL][64]
    int* __restrict__ plane_pi) {        // [NPL][64]
  const int plane = blockIdx.x;
  const int tid = threadIdx.x;

  __shared__ unsigned long long s_key[CAP];   // 16 KB raw candidates
  __shared__ unsigned long long c_key[CAP];   // 16 KB grouped (aliases fb_hist)
  __shared__ int s_off[SEGBLK + 1];
  __shared__ int cnt[RBK], suf[RBK], cur[RBK];
  __shared__ int s_flag, s_M, s_fast;
  __shared__ int s_fbB, s_fbAbove, s_fbT, s_fbCnt;

  if (tid == 0) { s_flag = 0; s_off[0] = 0; }
  __syncthreads();
  if (tid < SEGBLK) {
    int nv = counts[plane * SEGBLK + tid];
    if (nv > SEGCAP) { atomicOr(&s_flag, 1); nv = SEGCAP; }
    s_off[tid + 1] = nv;
  }
  __syncthreads();
  if (tid == 0) {
    int acc = 0;
    for (int i = 1; i <= SEGBLK; ++i) { acc += s_off[i]; s_off[i] = acc; }
    s_M = acc;
    s_fast = (s_flag == 0) && (acc >= KTOP) && (acc <= CAP);
  }
  __syncthreads();

  if (s_fast) {
    const unsigned long long* pk = segkey + (size_t)plane * SEGBLK * SEGCAP;
    for (int i = tid; i < SEGBLK * SEGCAP; i += 256) {
      const int sg = i >> 6;          // / SEGCAP
      const int j = i & (SEGCAP - 1);
      const int o = s_off[sg];
      const int nsg = s_off[sg + 1] - o;
      if (j < nsg) s_key[o + j] = pk[i];
    }
    __syncthreads();
  } else {
    // Exact radix-select rescan (values >= 0); never triggers on this data.
    const float* hp = heat + (size_t)plane * HWp;
    unsigned int* fb_hist = (unsigned int*)c_key;  // alias: c_key unused yet
    for (int i = tid; i < 1024; i += 256) fb_hist[i] = 0;
    __syncthreads();
    for_each_peak_plane(hp, tid, 256, [&](unsigned int bits, int idx) {
      unsigned int bkt = bits >> 20; if (bkt > 1023u) bkt = 1023u;
      atomicAdd(&fb_hist[bkt], 1u);
    });
    __syncthreads();
    if (tid == 0) {
      int acc = 0, Bs = -1;
      for (int bkt = 1023; bkt >= 0; --bkt) {
        int cc = (int)fb_hist[bkt];
        if (acc + cc >= KTOP) { Bs = bkt; s_fbAbove = acc; break; }
        acc += cc;
      }
      s_fbB = Bs;
      if (Bs < 0) s_fbAbove = acc;
    }
    __syncthreads();
    const int Bs = s_fbB;
    unsigned int T;
    if (Bs < 0) {
      T = 0;  // fewer than 50 peaks total: take them all
    } else {
      for (int i = tid; i < 1024; i += 256) fb_hist[i] = 0;
      __syncthreads();
      for_each_peak_plane(hp, tid, 256, [&](unsigned int bits, int idx) {
        unsigned int bkt = bits >> 20; if (bkt > 1023u) bkt = 1023u;
        if ((int)bkt == Bs) atomicAdd(&fb_hist[(bits >> 10) & 1023], 1u);
      });
      __syncthreads();
      if (tid == 0) {
        int acc = s_fbAbove, Ss = 0;
        for (int sb = 1023; sb >= 0; --sb) {
          int cc = (int)fb_hist[sb];
          if (acc + cc >= KTOP) { Ss = sb; break; }
          acc += cc;
        }
        s_fbT = (int)(((unsigned int)Bs << 20) | ((unsigned int)Ss << 10));
      }
      __syncthreads();
      T = (unsigned int)s_fbT;
    }
    if (tid == 0) s_fbCnt = 0;
    __syncthreads();
    for_each_peak_plane(hp, tid, 256, [&](unsigned int bits, int idx) {
      if (bits >= T) {
        int slot = atomicAdd(&s_fbCnt, 1);
        if (slot < CAP) s_key[slot] = mk_key(bits, idx);
      }
    });
    __syncthreads();
    if (tid == 0) s_M = s_fbCnt < CAP ? s_fbCnt : CAP;
    __syncthreads();
  }
  const int M = s_M;

  // ---- O(M) counting-sort rank: (value desc, idx asc) order. ----
  cnt[tid] = 0;
  cur[tid] = 0;
  __syncthreads();
  for (int i = tid; i < M; i += 256)
    atomicAdd(&cnt[bucket_of((unsigned int)(s_key[i] >> 32))], 1);
  __syncthreads();
  // Parallel suffix-sum (Hillis-Steele).
  suf[tid] = cnt[tid];
  __syncthreads();
#pragma unroll
  for (int d = 1; d < RBK; d <<= 1) {
    const int v = (tid + d < RBK) ? suf[tid + d] : 0;
    __syncthreads();
    suf[tid] += v;
    __syncthreads();
  }
  {
    const int excl = suf[tid] - cnt[tid];  // count of keys in buckets > tid
    __syncthreads();
    suf[tid] = excl;
  }
  __syncthreads();
  for (int i = tid; i < M; i += 256) {
    const unsigned long long k = s_key[i];
    const int bq = bucket_of((unsigned int)(k >> 32));
    const int slot = suf[bq] + atomicAdd(&cur[bq], 1);
    c_key[slot] = k;
  }
  __syncthreads();
  float* psc = plane_sc + plane * 64;
  int* ppi = plane_pi + plane * 64;
  for (int i = tid; i < M; i += 256) {
    const unsigned long long k = c_key[i];
    const int bq = bucket_of((unsigned int)(k >> 32));
    const int st = suf[bq];
    const int nb = cnt[bq];
    int rank = st;
    for (int tt = st; tt < st + nb; ++tt) rank += (c_key[tt] > k);
    if (rank < KTOP) {
      psc[rank] = __uint_as_float((unsigned int)(k >> 32));
      ppi[rank] = (int)~((unsigned int)k);
    }
  }
  for (int s2 = M + tid; s2 < KTOP; s2 += 256) {
    psc[s2] = 0.0f;
    ppi[s2] = 0;
  }
}

// ---------------------------------------------------------------------------
// Kernel 3: batch top-50 + 3D decode. 32 blocks x 256 threads.
// ---------------------------------------------------------------------------
__global__ __launch_bounds__(256) void decode_kernel(
    const float* __restrict__ plane_sc,  // [NPL][64]
    const int* __restrict__ plane_pi,    // [NPL][64]
    const float* __restrict__ regr,      // [B][8][HWp]
    const float* __restrict__ trans_mat, // [B][3][3]
    const float* __restrict__ K_mat,     // [B][3][3]
    const float* __restrict__ img_size,  // [B][2]
    float* __restrict__ out) {           // [B*50][14]
  const int b = blockIdx.x;
  const int tid = threadIdx.x;

  __shared__ float d_sc[NCLS * KTOP];
  __shared__ int d_pi[NCLS * KTOP];
  __shared__ int sel[KTOP];

  if (tid < NCLS * KTOP) {
    const int c = tid / KTOP;
    const int k2 = tid - c * KTOP;
    d_sc[tid] = plane_sc[(b * NCLS + c) * 64 + k2];
    d_pi[tid] = plane_pi[(b * NCLS + c) * 64 + k2];
  }
  __syncthreads();

  // Batch-level top-50 over 150 scores (tie: lower flattened position wins).
  if (tid < NCLS * KTOP) {
    const float v = d_sc[tid];
    int rank = 0;
    for (int j = 0; j < NCLS * KTOP; ++j) {
      const float w = d_sc[j];
      rank += (w > v) || (w == v && j < tid);
    }
    if (rank < KTOP) sel[rank] = tid;
  }
  __syncthreads();

  if (tid < KTOP) {
    const int i = sel[tid];
    const int cls = i / KTOP;
    const float score = d_sc[i];
    const int ind = d_pi[i];
    const float ys = (float)(ind / Wd);
    const float xs = (float)(ind - (ind / Wd) * Wd);

    const float* rb = regr + (size_t)b * 8 * HWp + ind;
    const float r0 = rb[0 * HWp], r1 = rb[1 * HWp], r2 = rb[2 * HWp], r3 = rb[3 * HWp];
    const float r4 = rb[4 * HWp], r5 = rb[5 * HWp], r6 = rb[6 * HWp], r7 = rb[7 * HWp];

    float tm[9], km[9], tmi[9], kmi[9];
#pragma unroll
    for (int q = 0; q < 9; ++q) { tm[q] = trans_mat[b * 9 + q]; km[q] = K_mat[b * 9 + q]; }
    inv3(tm, tmi);
    inv3(km, kmi);

    const float px = xs + r1, py = ys + r2;
    const float gx = tmi[0] * px + tmi[1] * py + tmi[2];
    const float gy = tmi[3] * px + tmi[4] * py + tmi[5];
    const float gz = tmi[6] * px + tmi[7] * py + tmi[8];
    const float depth = r0 * 16.32f + 28.01f;
    const float qx = gx * depth, qy = gy * depth, qz = gz * depth;
    const float lx = kmi[0] * qx + kmi[1] * qy + kmi[2] * qz;
    float ly = kmi[3] * qx + kmi[4] * qy + kmi[5] * qz;
    const float lz = kmi[6] * qx + kmi[7] * qy + kmi[8] * qz;

    const float d0 = expf(r3) * DIM_REF_C[cls * 3 + 0];
    const float d1 = expf(r4) * DIM_REF_C[cls * 3 + 1];
    const float d2 = expf(r5) * DIM_REF_C[cls * 3 + 2];
    ly += d1 * 0.5f;

    const float ray = atanf(lx / (lz + 1e-7f));
    float alpha = atanf(r6 / (r7 + 1e-7f));
    alpha += (r7 >= 0.0f) ? -PI_F * 0.5f : PI_F * 0.5f;
    const float roty = wrap_pi(alpha + ray);
    alpha = wrap_pi(alpha);

    const float SX[8] = {-0.5f, 0.5f, 0.5f, 0.5f, 0.5f, -0.5f, -0.5f, -0.5f};
    const float SY[8] = {-1.0f, -1.0f, 0.0f, 0.0f, -1.0f, -1.0f, 0.0f, 0.0f};
    const float SZ[8] = {-0.5f, -0.5f, -0.5f, 0.5f, 0.5f, 0.5f, 0.5f, -0.5f};
    const float cr = cosf(roty), sr = sinf(roty);
    float minx = INFINITY, maxx = -INFINITY, miny = INFINITY, maxy = -INFINITY;
#pragma unroll
    for (int j = 0; j < 8; ++j) {
      const float ax = d0 * SX[j], ay = d1 * SY[j], az = d2 * SZ[j];
      const float cx = cr * ax + sr * az + lx;
      const float cy = ay + ly;
      const float cz = -sr * ax + cr * az + lz;
      const float ppx = km[0] * cx + km[1] * cy + km[2] * cz;
      const float ppy = km[3] * cx + km[4] * cy + km[5] * cz;
      const float ppz = km[6] * cx + km[7] * cy + km[8] * cz;
      const float X = ppx / ppz, Y = ppy / ppz;
      minx = fminf(minx, X); maxx = fmaxf(maxx, X);
      miny = fminf(miny, Y); maxy = fmaxf(maxy, Y);
    }
    const float Wi = img_size[b * 2 + 0], Hi = img_size[b * 2 + 1];
    const float xmin = fminf(fmaxf(minx, 0.0f), Wi);
    const float ymin = fminf(fmaxf(miny, 0.0f), Hi);
    const float xmax = fminf(fmaxf(maxx, 0.0f), Wi);
    const float ymax = fminf(fmaxf(maxy, 0.0f), Hi);

    float* o = out + (size_t)(b * KTOP + tid) * 14;
    if (score > 0.25f) {
      o[0] = (float)cls; o[1] = alpha;
      o[2] = xmin; o[3] = ymin; o[4] = xmax; o[5] = ymax;
      o[6] = d1; o[7] = d2; o[8] = d0;   // dims rolled by -1
      o[9] = lx; o[10] = ly; o[11] = lz;
      o[12] = roty; o[13] = score;
    } else {
#pragma unroll
      for (int q = 0; q < 14; ++q) o[q] = 0.0f;
    }
  }
}

// ---------------------------------------------------------------------------

extern "C" void kernel_launch(void* const* d_in, const int* in_sizes, int n_in,
                              void* d_out, int out_size, void* d_ws, size_t ws_size,
                              hipStream_t stream) {
  const float* heat = (const float*)d_in[0];  // [32,3,192,640]
  const float* regr = (const float*)d_in[1];  // [32,8,192,640]
  const float* tmat = (const float*)d_in[2];  // [32,3,3]
  const float* kmat = (const float*)d_in[3];  // [32,3,3]
  const float* isz = (const float*)d_in[4];   // [32,2]

  char* ws = (char*)d_ws;
  int* counts = (int*)(ws + OFF_COUNTS);
  unsigned long long* segkey = (unsigned long long*)(ws + OFF_SEGKEY);
  float* plane_sc = (float*)(ws + OFF_PSC);
  int* plane_pi = (int*)(ws + OFF_PPI);

  scan_kernel<<<NPL * SEGBLK, 256, 0, stream>>>(heat, counts, segkey);
  rank_kernel<<<NPL, 256, 0, stream>>>(heat, counts, segkey,
                                       plane_sc, plane_pi);
  decode_kernel<<<NB, 256, 0, stream>>>(plane_sc, plane_pi,
                                        regr, tmat, kmat, isz,
                                        (float*)d_out);
}